// Round 2
// baseline (704.502 us; speedup 1.0000x reference)
//
#include <hip/hip_runtime.h>
#include <hip/hip_bf16.h>
#include <math.h>

// All float tensors are float32 (per the reference); edge_index is int32.
// Output: float32 sigmoid scores per original edge.
//
// Decomposition (self-loops handled analytically, never materialized):
//   deg[v]  = #{e : col[e]==v} + 1
//   dinv[v] = rsqrt(deg[v])
//   ts[v]   = (h[v] @ W) * dinv[v]
//   agg[c]  = dinv[c] * ( sum_{e: col[e]==c} ts[row[e]]  +  ts[c] )
//   h'      = agg + b   (ReLU after layer 1)
//   score_e = sigmoid( dot(h2[row_e], h2[col_e]) )   (original edges only)

__global__ void k_count(const int* __restrict__ col, float* __restrict__ deg, int E) {
    int e = blockIdx.x * 256 + threadIdx.x;
    if (e < E) atomicAdd(&deg[col[e]], 1.0f);
}

__global__ void k_dinv(float* __restrict__ dinv, int N) {
    int v = blockIdx.x * 256 + threadIdx.x;
    if (v < N) dinv[v] = rsqrtf(dinv[v] + 1.0f);  // +1 = self-loop
}

// ts[v][c] = (sum_k x[v][k] * W1[k][c]) * dinv[v];  16 nodes per 256-thread block.
__global__ __launch_bounds__(256) void k_gemm1(
    const float* __restrict__ x, const float* __restrict__ W1,
    const float* __restrict__ dinv, float* __restrict__ ts, int N) {
    __shared__ float xs[16 * 132];   // stride 132 breaks the power-of-2 bank pattern
    __shared__ float ws[128 * 16];
    const int tid = threadIdx.x;
    const int base = blockIdx.x * 16;

    {   // W1: (128,16) fp32 = 512 float4; flat copy, 2 per thread
        const float4* wp = (const float4*)W1;
        float4* wd = (float4*)ws;
        wd[tid] = wp[tid];
        wd[tid + 256] = wp[tid + 256];
    }
    {   // x tile: 16 rows x 128 fp32 = 512 float4; 2 per thread, padded rows
        const float4* xp = (const float4*)(x + (size_t)base * 128);
        #pragma unroll
        for (int i = 0; i < 2; ++i) {
            int idx = tid + i * 256;
            float4 u = xp[idx];
            int r = idx >> 5, c4 = (idx & 31) * 4;   // 32 float4 per row
            float* d = &xs[r * 132 + c4];
            d[0] = u.x; d[1] = u.y; d[2] = u.z; d[3] = u.w;
        }
    }
    __syncthreads();

    const int r = tid >> 4, c = tid & 15;
    float acc = 0.f;
    #pragma unroll
    for (int k = 0; k < 128; ++k) acc = fmaf(xs[r * 132 + k], ws[k * 16 + c], acc);
    const int v = base + r;
    ts[(size_t)v * 16 + c] = acc * dinv[v];
}

// 16 lanes per edge: lane c does acc[col*16+c] += ts[row*16+c]
__global__ void k_scatter(const int* __restrict__ row, const int* __restrict__ col,
                          const float* __restrict__ ts, float* __restrict__ acc, int E) {
    int g = blockIdx.x * 256 + threadIdx.x;
    int e = g >> 4, c = g & 15;
    if (e < E) {
        int r = row[e], t = col[e];
        float val = ts[(size_t)r * 16 + c];
        atomicAdd(&acc[(size_t)t * 16 + c], val);
    }
}

// h[v][c] = act( dinv[v]*(acc[v][c] + ts[v][c]) + b[c] ), in place into acc
__global__ void k_finalize(float* __restrict__ acc, const float* __restrict__ ts,
                           const float* __restrict__ dinv, const float* __restrict__ b,
                           int N, int relu) {
    int g = blockIdx.x * 256 + threadIdx.x;
    int v = g >> 4, c = g & 15;
    if (v < N) {
        float h = dinv[v] * (acc[g] + ts[g]) + b[c];
        if (relu) h = fmaxf(h, 0.f);
        acc[g] = h;
    }
}

// ts2[v][c] = (sum_k h1[v][k] * W2[k][c]) * dinv[v]
__global__ __launch_bounds__(256) void k_gemm2(
    const float* __restrict__ h1, const float* __restrict__ W2,
    const float* __restrict__ dinv, float* __restrict__ ts2, int N) {
    __shared__ float hs[16 * 17];   // +1 pad
    __shared__ float ws[256];
    const int tid = threadIdx.x;
    const int base = blockIdx.x * 16;

    if (tid < 64) {  // W2: (16,16) fp32 = 64 float4, flat copy
        ((float4*)ws)[tid] = ((const float4*)W2)[tid];
    }
    if (tid >= 64 && tid < 128) {  // h1 tile: 16x16 fp32 = 64 float4
        int t = tid - 64;
        const float4* hp = (const float4*)(h1 + (size_t)base * 16);
        float4 v4 = hp[t];
        int r = t >> 2, c0 = (t & 3) * 4;
        float* d = &hs[r * 17 + c0];
        d[0] = v4.x; d[1] = v4.y; d[2] = v4.z; d[3] = v4.w;
    }
    __syncthreads();

    const int r = tid >> 4, c = tid & 15;
    float acc = 0.f;
    #pragma unroll
    for (int k = 0; k < 16; ++k) acc = fmaf(hs[r * 17 + k], ws[k * 16 + c], acc);
    const int v = base + r;
    ts2[(size_t)v * 16 + c] = acc * dinv[v];
}

__global__ void k_score(const int* __restrict__ row, const int* __restrict__ col,
                        const float* __restrict__ h2, float* __restrict__ out, int E) {
    int e = blockIdx.x * 256 + threadIdx.x;
    if (e < E) {
        const float4* a = (const float4*)(h2 + (size_t)row[e] * 16);
        const float4* b = (const float4*)(h2 + (size_t)col[e] * 16);
        float d = 0.f;
        #pragma unroll
        for (int i = 0; i < 4; ++i) {
            float4 u = a[i], v = b[i];
            d += u.x * v.x + u.y * v.y + u.z * v.z + u.w * v.w;
        }
        out[e] = 1.0f / (1.0f + __expf(-d));
    }
}

extern "C" void kernel_launch(void* const* d_in, const int* in_sizes, int n_in,
                              void* d_out, int out_size, void* d_ws, size_t ws_size,
                              hipStream_t stream) {
    const float* x  = (const float*)d_in[0];
    const int*   ei = (const int*)d_in[1];
    const float* W1 = (const float*)d_in[2];
    const float* b1 = (const float*)d_in[3];
    const float* W2 = (const float*)d_in[4];
    const float* b2 = (const float*)d_in[5];

    const int N = in_sizes[0] / 128;   // 100000 (multiple of 16)
    const int E = in_sizes[1] / 2;     // 3200000
    const int* row = ei;
    const int* col = ei + E;

    char* ws = (char*)d_ws;
    float* dinv = (float*)(ws);                                   // N * 4 B
    float* ts   = (float*)(ws + (size_t)N * 4);                   // N * 64 B
    float* acc  = (float*)(ws + (size_t)N * 4 + (size_t)N * 64);  // N * 64 B
    // total ws use: N * 132 B = 13.2 MB

    float* out = (float*)d_out;

    hipMemsetAsync(dinv, 0, (size_t)N * 4, stream);
    hipMemsetAsync(acc, 0, (size_t)N * 64, stream);

    k_count<<<(E + 255) / 256, 256, 0, stream>>>(col, dinv, E);
    k_dinv<<<(N + 255) / 256, 256, 0, stream>>>(dinv, N);

    // Layer 1
    k_gemm1<<<N / 16, 256, 0, stream>>>(x, W1, dinv, ts, N);
    k_scatter<<<(E * 16) / 256, 256, 0, stream>>>(row, col, ts, acc, E);
    k_finalize<<<(N * 16 + 255) / 256, 256, 0, stream>>>(acc, ts, dinv, b1, N, 1);

    // Layer 2 (gemm2 reads acc=h1, writes ts; then acc re-zeroed for aggregation)
    k_gemm2<<<N / 16, 256, 0, stream>>>(acc, W2, dinv, ts, N);
    hipMemsetAsync(acc, 0, (size_t)N * 64, stream);
    k_scatter<<<(E * 16) / 256, 256, 0, stream>>>(row, col, ts, acc, E);
    k_finalize<<<(N * 16 + 255) / 256, 256, 0, stream>>>(acc, ts, dinv, b2, N, 0);

    // Edge scores over original edges
    k_score<<<(E + 255) / 256, 256, 0, stream>>>(row, col, acc, out, E);
}